// Round 17
// baseline (117.718 us; speedup 1.0000x reference)
//
#include <hip/hip_runtime.h>
#include <math.h>

#define DD 768
#define SS 1024
#define BB 2
#define HH 12
#define DH 64

typedef __attribute__((ext_vector_type(8))) short bf16x8;
typedef __attribute__((ext_vector_type(8))) unsigned short u16x8;
typedef __attribute__((ext_vector_type(4))) float f32x4;

// ---- workspace layout (ushort units) ----
constexpr size_t O_GATEIN = 0;                                   // [2048][2304] bf16
constexpr size_t O_WPROJT = O_GATEIN + (size_t)2048 * 2304;      // [4608][768]
constexpr size_t O_WG1T   = O_WPROJT + (size_t)4608 * 768;       // [768][2304]
constexpr size_t O_WG2T   = O_WG1T + (size_t)768 * 2304;         // [768][768]
constexpr size_t O_WOUTT  = O_WG2T + (size_t)768 * 768;          // [768][768]
constexpr size_t O_PROJ   = O_WOUTT + (size_t)768 * 768;         // [2048][4608] (regions 0,3,4 used)
constexpr size_t O_KFT    = O_PROJ + (size_t)2048 * 4608;        // [2][768][1024]
constexpr size_t O_VLT    = O_KFT + (size_t)2 * 768 * 1024;      // [2][768][1024]
constexpr size_t O_VOT    = O_VLT + (size_t)2 * 768 * 1024;      // [2][12][64][1024]
constexpr size_t O_KVT    = O_VOT + (size_t)2 * 768 * 1024;      // [2][768][768]
constexpr size_t O_H1     = O_KVT + (size_t)2 * 768 * 768;       // [2048][768]
constexpr size_t O_FUSED  = O_H1 + (size_t)2048 * 768;           // [2048][768]
constexpr size_t O_F32    = O_FUSED + (size_t)2048 * 768;        // f32 area

__device__ inline unsigned short f2bf(float f) {
    unsigned int u = __builtin_bit_cast(unsigned int, f);
    unsigned int r = (u + 0x7fffu + ((u >> 16) & 1u)) >> 16;
    return (unsigned short)r;
}
__device__ inline float bf2f(unsigned short h) {
    unsigned int u = ((unsigned int)h) << 16;
    return __builtin_bit_cast(float, u);
}
__device__ inline void gload16(const ushort* g, ushort* l) {
    __builtin_amdgcn_global_load_lds((const __attribute__((address_space(1))) void*)g,
                                     (__attribute__((address_space(3))) void*)l, 16, 0, 0);
}

// ---------------- prep: weight transposes + bias concat + LayerNorm (+kfsum zero) ----------------
struct PrepArgs {
    const float* src[11];
    unsigned long long dstOff[11];
    int ldo[11];
    const float* bsrc[6];
    float* bdst;
    const float* x;
    const float* gamma;
    const float* beta;
    float* kfsum;
};
__global__ __launch_bounds__(256) void prep_kernel(PrepArgs a, ushort* __restrict__ wsb) {
    __shared__ float t[32][33];
    __shared__ float ws1[4], ws2[4], mstat[2];
    int bid = blockIdx.x;
    int tid = threadIdx.x;
    if (bid < 6336) {
        int z = bid / 576;
        int rem = bid - z * 576;
        int r0 = (rem / 24) * 32, c0 = (rem % 24) * 32;
        const float* ip = a.src[z];
        ushort* op = wsb + a.dstOff[z];
        int ldo = a.ldo[z];
        int tx = tid & 31, ty = tid >> 5;
        #pragma unroll
        for (int i = 0; i < 32; i += 8) t[ty + i][tx] = ip[(size_t)(r0 + ty + i) * 768 + c0 + tx];
        __syncthreads();
        #pragma unroll
        for (int i = 0; i < 32; i += 8) op[(size_t)(c0 + ty + i) * ldo + r0 + tx] = f2bf(t[tx][ty + i]);
        return;
    }
    if (bid < 6354) {
        int i = (bid - 6336) * 256 + tid;
        if (i < 4608) a.bdst[i] = a.bsrc[i / 768][i % 768];
        return;
    }
    int row = bid - 6354;
    if (row == 0) {
        #pragma unroll
        for (int i = 0; i < 6; ++i) a.kfsum[tid + i * 256] = 0.f;
    }
    const float* xr = a.x + (size_t)row * DD;
    ushort* outr = wsb + O_GATEIN + (size_t)row * 2304 + 1536;
    float v[3];
    float s = 0.f, s2 = 0.f;
    #pragma unroll
    for (int r = 0; r < 3; ++r) {
        v[r] = xr[tid + r * 256];
        s += v[r];
        s2 += v[r] * v[r];
    }
    #pragma unroll
    for (int o = 32; o > 0; o >>= 1) {
        s  += __shfl_down(s, o);
        s2 += __shfl_down(s2, o);
    }
    int wid = tid >> 6, lane = tid & 63;
    if (lane == 0) { ws1[wid] = s; ws2[wid] = s2; }
    __syncthreads();
    if (tid == 0) {
        float aa = 0.f, b2 = 0.f;
        #pragma unroll
        for (int i = 0; i < 4; ++i) { aa += ws1[i]; b2 += ws2[i]; }
        float mean = aa / (float)DD;
        float var = b2 / (float)DD - mean * mean;
        mstat[0] = mean;
        mstat[1] = rsqrtf(var + 1e-5f);
    }
    __syncthreads();
    float mean = mstat[0], rstd = mstat[1];
    #pragma unroll
    for (int r = 0; r < 3; ++r) {
        int i = tid + r * 256;
        outr[i] = f2bf((v[r] - mean) * rstd * a.gamma[i] + a.beta[i]);
    }
}

// ---------------- MFMA bf16 GEMM device body ----------------
// Counted-vmcnt 2-phase pipeline: stage(kt+1); vmcnt(NLD); s_barrier; MFMA; s_barrier.
// T2 swizzle: TPR>=8 -> row&(TPR-1); TPR==4 -> (row>>1)&3.
// mode 0: plain; mode 1 (TM=128,TN=128): fused projection scatter (+kfsum atomics via rowdiv);
// mode 2: gate2+fuse.
template<int TM, int TN, int BK>
__device__ __forceinline__ void gemm_dev(
    ushort* lds, int bx, int by, int bz,
    const ushort* __restrict__ A, const ushort* __restrict__ B,
    ushort* __restrict__ wsb,
    float* __restrict__ Cf, ushort* __restrict__ Cb,
    const float* __restrict__ bias, const float* __restrict__ rowdiv,
    const float* __restrict__ addsrc,
    int M, int N, int K, int lda, int ldb, int ldcf, int ldcb,
    long long bA, long long bB, long long bCf, long long bCb,
    int act, int mode) {
    constexpr int MF = TM / 32;
    constexpr int NF = TN / 32;
    constexpr int TPR = BK / 8;              // threads per row (staging)
    constexpr int ROWS = 2048 / BK;          // rows per staging round
    constexpr int AR = TM * BK / 2048;       // A staging rounds
    constexpr int BR = TN * BK / 2048;       // B staging rounds
    constexpr int NLD = AR + BR;
    constexpr int ABUF = TM * BK;
    constexpr int BBUF = TN * BK;
    const int tid = threadIdx.x, wid = tid >> 6, lane = tid & 63;
    const int m0 = by * TM, n0 = bx * TN, z = bz;
    const ushort* Az = A + (size_t)z * bA;
    const ushort* Bz = B + (size_t)z * bB;
    const int trow = tid / TPR;
    const int ssel = (TPR >= 8) ? (trow & (TPR - 1)) : ((trow >> 1) & 3);
    const int scol = ((tid % TPR) ^ ssel) * 8;
    const int wm = wid >> 1, wn = wid & 1;
    const int fr = lane & 15, fq = lane >> 4;
    const int rsel = (TPR >= 8) ? (fr & (TPR - 1)) : ((fr >> 1) & 3);
    f32x4 acc[MF][NF];
    #pragma unroll
    for (int i = 0; i < MF; ++i)
        #pragma unroll
        for (int j = 0; j < NF; ++j) acc[i][j] = f32x4{0.f, 0.f, 0.f, 0.f};
    const int nkt = K / BK;

    auto stage = [&](int t) {
        const int k0 = t * BK;
        const int bsel = t & 1;
        #pragma unroll
        for (int i = 0; i < AR; ++i)
            gload16(Az + (size_t)(m0 + i * ROWS + trow) * lda + k0 + scol,
                    &lds[bsel * ABUF + i * 2048 + wid * 512]);
        #pragma unroll
        for (int i = 0; i < BR; ++i)
            gload16(Bz + (size_t)(n0 + i * ROWS + trow) * ldb + k0 + scol,
                    &lds[2 * ABUF + bsel * BBUF + i * 2048 + wid * 512]);
    };

    stage(0);
    for (int kt = 0; kt < nkt; ++kt) {
        if (kt + 1 < nkt) {
            stage(kt + 1);
            if constexpr (NLD == 3)      asm volatile("s_waitcnt vmcnt(3)" ::: "memory");
            else if constexpr (NLD == 4) asm volatile("s_waitcnt vmcnt(4)" ::: "memory");
            else if constexpr (NLD == 5) asm volatile("s_waitcnt vmcnt(5)" ::: "memory");
            else if constexpr (NLD == 6) asm volatile("s_waitcnt vmcnt(6)" ::: "memory");
            else                         asm volatile("s_waitcnt vmcnt(8)" ::: "memory");
        } else {
            asm volatile("s_waitcnt vmcnt(0)" ::: "memory");
        }
        __builtin_amdgcn_s_barrier();
        const ushort* As = &lds[(kt & 1) * ABUF];
        const ushort* Bs = &lds[2 * ABUF + (kt & 1) * BBUF];
        #pragma unroll
        for (int ks = 0; ks < BK / 32; ++ks) {
            const int ck = (((ks * 4 + fq) ^ rsel) << 3);
            bf16x8 af[MF], bfr[NF];
            #pragma unroll
            for (int mf = 0; mf < MF; ++mf)
                af[mf] = *(const bf16x8*)&As[(wm * (TM / 2) + mf * 16 + fr) * BK + ck];
            #pragma unroll
            for (int nf = 0; nf < NF; ++nf)
                bfr[nf] = *(const bf16x8*)&Bs[(wn * (TN / 2) + nf * 16 + fr) * BK + ck];
            #pragma unroll
            for (int mf = 0; mf < MF; ++mf)
                #pragma unroll
                for (int nf = 0; nf < NF; ++nf)
                    acc[mf][nf] = __builtin_amdgcn_mfma_f32_16x16x32_bf16(af[mf], bfr[nf], acc[mf][nf], 0, 0, 0);
        }
        asm volatile("" ::: "memory");
        __builtin_amdgcn_s_barrier();
    }

    if constexpr (TM == 128 && TN == 128) {
        if (mode == 1) {
            const int region = n0 / 768;
            const int ncol = n0 - region * 768;
            const int b = m0 >> 10, s0 = m0 & 1023;
            const bool transposed = (region == 1 || region == 2 || region == 5);
            if (!transposed) {
                #pragma unroll
                for (int mf = 0; mf < MF; ++mf) {
                    #pragma unroll
                    for (int j = 0; j < 4; ++j) {
                        int m = m0 + wm * 64 + mf * 16 + fq * 4 + j;
                        #pragma unroll
                        for (int nf = 0; nf < NF; ++nf) {
                            int n = n0 + wn * 64 + nf * 16 + fr;
                            float t = acc[mf][nf][j] + bias[n];
                            if (region == 0) t = (t > 0.f) ? t + 1.f : expf(t);
                            wsb[O_PROJ + (size_t)m * 4608 + n] = f2bf(t);
                        }
                    }
                }
            } else {
                float psum[NF];
                #pragma unroll
                for (int i = 0; i < NF; ++i) psum[i] = 0.f;
                #pragma unroll
                for (int mf = 0; mf < MF; ++mf) {
                    #pragma unroll
                    for (int nf = 0; nf < NF; ++nf) {
                        int d_l = wn * 64 + nf * 16 + fr;
                        float bs = bias[n0 + d_l];
                        #pragma unroll
                        for (int j = 0; j < 4; ++j) {
                            int s_l = wm * 64 + mf * 16 + fq * 4 + j;
                            float t = acc[mf][nf][j] + bs;
                            if (region == 1) { t = (t > 0.f) ? t + 1.f : expf(t); psum[nf] += t; }
                            lds[d_l * 136 + s_l] = f2bf(t);
                        }
                    }
                }
                if (region == 1 && rowdiv) {
                    // kfsum: reduce over fq group (lanes ^16, ^32), one atomic per (wave, nf, fr)
                    #pragma unroll
                    for (int nf = 0; nf < NF; ++nf) {
                        float s = psum[nf];
                        s += __shfl_xor(s, 16);
                        s += __shfl_xor(s, 32);
                        if (fq == 0)
                            atomicAdd((float*)rowdiv + b * 768 + ncol + wn * 64 + nf * 16 + fr, s);
                    }
                }
                __syncthreads();
                size_t dstT = (region == 1) ? O_KFT : (region == 2) ? O_VLT : O_VOT;
                #pragma unroll
                for (int dd = 0; dd < 8; ++dd) {
                    int d_l = wid * 32 + dd * 4 + (lane >> 4);
                    int sc8 = (lane & 15) * 8;
                    u16x8 v = *(const u16x8*)&lds[d_l * 136 + sc8];
                    *(u16x8*)&wsb[dstT + (size_t)(b * 768 + ncol + d_l) * 1024 + s0 + sc8] = v;
                }
            }
            return;
        }
    }

    float* cfz = Cf ? Cf + (size_t)z * bCf : nullptr;
    ushort* cbz = Cb ? Cb + (size_t)z * bCb : nullptr;
    #pragma unroll
    for (int mf = 0; mf < MF; ++mf) {
        #pragma unroll
        for (int j = 0; j < 4; ++j) {
            int m = m0 + wm * (TM / 2) + mf * 16 + fq * 4 + j;
            float rd = rowdiv ? 1.f / (rowdiv[(size_t)z * M + m] + 1e-6f) : 1.f;
            #pragma unroll
            for (int nf = 0; nf < NF; ++nf) {
                int n = n0 + wn * (TN / 2) + nf * 16 + fr;
                float v = acc[mf][nf][j];
                if (bias) v += bias[n];
                v *= rd;
                if (act == 1) v = (v > 0.f) ? v + 1.f : expf(v);
                else if (act == 2) v = fmaxf(v, 0.f);
                else if (act == 3) v = 1.f / (1.f + expf(-v));
                if (mode == 2) {
                    float lin = bf2f(wsb[O_GATEIN + (size_t)m * 2304 + n]);
                    float win = bf2f(wsb[O_GATEIN + (size_t)m * 2304 + 768 + n]);
                    v = v * lin + (1.f - v) * win;
                }
                if (addsrc) v += addsrc[(size_t)m * ldcf + n];
                if (cfz) cfz[(size_t)m * ldcf + n] = v;
                if (cbz) cbz[(size_t)m * ldcb + n] = f2bf(v);
            }
        }
    }
}

template<int TM, int TN, int BK>
__global__ __launch_bounds__(256) void gemm_bf16(
    const ushort* __restrict__ A, const ushort* __restrict__ B,
    ushort* __restrict__ wsb,
    float* __restrict__ Cf, ushort* __restrict__ Cb,
    const float* __restrict__ bias, const float* __restrict__ rowdiv,
    const float* __restrict__ addsrc,
    int M, int N, int K, int lda, int ldb, int ldcf, int ldcb,
    long long bA, long long bB, long long bCf, long long bCb,
    int act, int mode) {
    constexpr int PIPE = 2 * TM * BK + 2 * TN * BK;
    constexpr int EPIL = (TM == 128 && TN == 128) ? 128 * 136 : 0;
    constexpr int LDSE = (PIPE > EPIL) ? PIPE : EPIL;
    __shared__ __align__(16) ushort lds[LDSE];
    // T1 XCD swizzle (bijective; all grids %8==0)
    int nwg = gridDim.x * gridDim.y;
    int flat = blockIdx.y * gridDim.x + blockIdx.x;
    int q = nwg >> 3;
    int nf = (flat & 7) * q + (flat >> 3);
    int bx = nf / gridDim.y;
    int by = nf % gridDim.y;
    gemm_dev<TM, TN, BK>(lds, bx, by, blockIdx.z, A, B, wsb, Cf, Cb,
                         bias, rowdiv, addsrc, M, N, K, lda, ldb, ldcf, ldcb,
                         bA, bB, bCf, bCb, act, mode);
}

// ---------------- merged kvT GEMM + windowed attention + normalizer ----------------
__global__ __launch_bounds__(256) void kv_attn(ushort* __restrict__ wsb,
                                               const float* __restrict__ kfsum,
                                               float* __restrict__ nrm) {
    __shared__ __align__(16) ushort lds[2 * 32 * 64 + 2 * 128 * 64];   // 20480 ushorts
    int bid = blockIdx.x;
    int tid = threadIdx.x;
    if (bid < 288) {
        int bx = bid % 6, by = (bid / 6) % 24, bz = bid / 144;
        gemm_dev<32, 128, 64>(lds, bx, by, bz,
            wsb + O_VLT, wsb + O_KFT, wsb, nullptr, wsb + O_KVT,
            nullptr, nullptr, nullptr,
            768, 768, 1024, 1024, 1024, 0, 768,
            (long long)768 * 1024, (long long)768 * 1024, 0, (long long)768 * 768, 0, 0);
        return;
    }
    if (bid >= 672) {
        int r = tid >> 3, p = tid & 7;
        int row = (bid - 672) * 32 + r;
        int b = row >> 10;
        const ushort* qrow = wsb + O_PROJ + (size_t)row * 4608 + p * 96;
        const float* kb = kfsum + b * 768 + p * 96;
        float s = 0.f;
        #pragma unroll
        for (int i = 0; i < 96; i += 8) {
            u16x8 v = *(const u16x8*)&qrow[i];
            #pragma unroll
            for (int j = 0; j < 8; ++j) s += bf2f(v[j]) * kb[i + j];
        }
        s += __shfl_xor(s, 1);
        s += __shfl_xor(s, 2);
        s += __shfl_xor(s, 4);
        if (p == 0) nrm[row] = s;
        return;
    }
    int a = bid - 288;
    int qx = a % 16, h = (a / 16) % 12, b = a / 192;
    ushort* Ps = lds;
    int wq = tid >> 6, lane = tid & 63;
    int fq = lane >> 4, fr = lane & 15;
    int q0 = qx * 64;
    const ushort* Pb = wsb + O_PROJ + (size_t)(b * SS) * 4608;
    const ushort* Vb = wsb + O_VOT + (size_t)(b * 768 + h * 64) * 1024;
    const int qoff = 2304 + h * 64, koff = 3072 + h * 64;

    int qrow = q0 + wq * 16 + fr;
    bf16x8 aq0 = *(const bf16x8*)&Pb[(size_t)qrow * 4608 + qoff + fq * 8];
    bf16x8 aq1 = *(const bf16x8*)&Pb[(size_t)qrow * 4608 + qoff + 32 + fq * 8];

    f32x4 sc[8];
    #pragma unroll
    for (int nf = 0; nf < 8; ++nf) sc[nf] = f32x4{0.f, 0.f, 0.f, 0.f};
    #pragma unroll
    for (int nf = 0; nf < 8; ++nf) {
        int kr = q0 - 32 + nf * 16 + fr;
        int kc = kr < 0 ? 0 : (kr > 1023 ? 1023 : kr);
        bf16x8 bk0 = *(const bf16x8*)&Pb[(size_t)kc * 4608 + koff + fq * 8];
        bf16x8 bk1 = *(const bf16x8*)&Pb[(size_t)kc * 4608 + koff + 32 + fq * 8];
        sc[nf] = __builtin_amdgcn_mfma_f32_16x16x32_bf16(aq0, bk0, sc[nf], 0, 0, 0);
        sc[nf] = __builtin_amdgcn_mfma_f32_16x16x32_bf16(aq1, bk1, sc[nf], 0, 0, 0);
    }

    float p[8][4];
    float inv[4];
    #pragma unroll
    for (int j = 0; j < 4; ++j) {
        int qt = wq * 16 + fq * 4 + j;
        float sv[8];
        float mx = -1e30f;
        #pragma unroll
        for (int nf = 0; nf < 8; ++nf) {
            int c = nf * 16 + fr;
            int kg = q0 - 32 + c;
            bool val = (c >= qt) && (c <= qt + 64) && (kg >= 0) && (kg < SS);
            float t = sc[nf][j] * 0.125f;
            sv[nf] = val ? t : -1e30f;
            mx = fmaxf(mx, sv[nf]);
        }
        mx = fmaxf(mx, __shfl_xor(mx, 1));
        mx = fmaxf(mx, __shfl_xor(mx, 2));
        mx = fmaxf(mx, __shfl_xor(mx, 4));
        mx = fmaxf(mx, __shfl_xor(mx, 8));
        float dn = 0.f;
        #pragma unroll
        for (int nf = 0; nf < 8; ++nf) {
            float e = expf(sv[nf] - mx);
            p[nf][j] = e;
            dn += e;
        }
        dn += __shfl_xor(dn, 1);
        dn += __shfl_xor(dn, 2);
        dn += __shfl_xor(dn, 4);
        dn += __shfl_xor(dn, 8);
        inv[j] = 1.f / dn;
    }

    #pragma unroll
    for (int nf = 0; nf < 8; ++nf) {
        int chunk = nf * 2 + (fr >> 3);
        #pragma unroll
        for (int j = 0; j < 4; ++j) {
            int r = fq * 4 + j;
            Ps[wq * 2048 + r * 128 + ((chunk ^ r) * 8) + (fr & 7)] = f2bf(p[nf][j] * inv[j]);
        }
    }
    __syncthreads();

    f32x4 oa[4];
    #pragma unroll
    for (int nf = 0; nf < 4; ++nf) oa[nf] = f32x4{0.f, 0.f, 0.f, 0.f};
    #pragma unroll
    for (int ks = 0; ks < 4; ++ks) {
        bf16x8 pa = *(const bf16x8*)&Ps[wq * 2048 + fr * 128 + (((ks * 4 + fq) ^ fr) * 8)];
        #pragma unroll
        for (int nf = 0; nf < 4; ++nf) {
            int dr = nf * 16 + fr;
            const ushort* vp = Vb + (ptrdiff_t)dr * 1024 + (q0 - 32 + ks * 32 + fq * 8);
            bf16x8 bv = *(const bf16x8*)vp;
            oa[nf] = __builtin_amdgcn_mfma_f32_16x16x32_bf16(pa, bv, oa[nf], 0, 0, 0);
        }
    }

    #pragma unroll
    for (int nf = 0; nf < 4; ++nf) {
        int d = nf * 16 + fr;
        #pragma unroll
        for (int j = 0; j < 4; ++j) {
            int q = q0 + wq * 16 + fq * 4 + j;
            wsb[O_GATEIN + (size_t)(b * SS + q) * 2304 + 768 + h * 64 + d] = f2bf(oa[nf][j]);
        }
    }
}

extern "C" void kernel_launch(void* const* d_in, const int* in_sizes, int n_in,
                              void* d_out, int out_size, void* d_ws, size_t ws_size,
                              hipStream_t stream) {
    const float* x      = (const float*)d_in[0];
    const float* W_q    = (const float*)d_in[1];
    const float* b_q    = (const float*)d_in[2];
    const float* W_k    = (const float*)d_in[3];
    const float* b_k    = (const float*)d_in[4];
    const float* W_v    = (const float*)d_in[5];
    const float* b_v    = (const float*)d_in[6];
    const float* W_ql   = (const float*)d_in[7];
    const float* b_ql   = (const float*)d_in[8];
    const float* W_kl   = (const float*)d_in[9];
    const float* b_kl   = (const float*)d_in[10];
    const float* W_vl   = (const float*)d_in[11];
    const float* b_vl   = (const float*)d_in[12];
    const float* W_out  = (const float*)d_in[13];
    const float* b_out  = (const float*)d_in[14];
    const float* W_g1   = (const float*)d_in[15];
    const float* b_g1   = (const float*)d_in[16];
    const float* W_g2   = (const float*)d_in[17];
    const float* b_g2   = (const float*)d_in[18];
    const float* gamma1 = (const float*)d_in[19];
    const float* beta1  = (const float*)d_in[20];

    ushort* wsb = (ushort*)d_ws;
    float* f32a = (float*)(wsb + O_F32);
    float* bias_cat = f32a;            // 4608
    float* kfsum    = f32a + 4608;     // 1536
    float* nrm      = kfsum + 1536;    // 2048

    const long long W2 = (long long)768 * 768;

    // 1. prep: weight transposes + bias concat + LayerNorm (+ kfsum zero)
    PrepArgs pa;
    const float* wsrc[6] = {W_q, W_k, W_v, W_ql, W_kl, W_vl};
    for (int i = 0; i < 6; ++i) { pa.src[i] = wsrc[i]; pa.dstOff[i] = O_WPROJT + i * W2; pa.ldo[i] = 768; }
    for (int i = 0; i < 3; ++i) { pa.src[6 + i] = W_g1 + (size_t)i * 768 * 768; pa.dstOff[6 + i] = O_WG1T + i * 768; pa.ldo[6 + i] = 2304; }
    pa.src[9] = W_g2;  pa.dstOff[9] = O_WG2T;  pa.ldo[9] = 768;
    pa.src[10] = W_out; pa.dstOff[10] = O_WOUTT; pa.ldo[10] = 768;
    const float* bsrc[6] = {b_q, b_k, b_v, b_ql, b_kl, b_vl};
    for (int i = 0; i < 6; ++i) pa.bsrc[i] = bsrc[i];
    pa.bdst = bias_cat;
    pa.x = x; pa.gamma = gamma1; pa.beta = beta1;
    pa.kfsum = kfsum;
    prep_kernel<<<dim3(8402), 256, 0, stream>>>(pa, wsb);

    // 2. fused 6-way projection (mode 1; proven round-15 config: 128x128 BK=32)
    gemm_bf16<128, 128, 32><<<dim3(36, 16, 1), 256, 0, stream>>>(
        wsb + O_GATEIN + 1536, wsb + O_WPROJT, wsb, nullptr, nullptr, bias_cat, kfsum, nullptr,
        2048, 4608, 768, 2304, 768, 0, 0, 0, 0, 0, 0, 0, 1);

    // 3. kvT GEMM + windowed attention + normalizer (merged full-machine pass)
    kv_attn<<<dim3(736), 256, 0, stream>>>(wsb, kfsum, nrm);

    // 4. lin = (qf @ kvT^T)/nrm -> gate_in slice 0   (BK=128: 6 K-steps)
    gemm_bf16<32, 64, 128><<<dim3(12, 32, 2), 256, 0, stream>>>(
        wsb + O_PROJ, wsb + O_KVT, wsb, nullptr, wsb + O_GATEIN, nullptr, nrm, nullptr,
        1024, 768, 768, 4608, 768, 0, 2304,
        (long long)1024 * 4608, W2, 0, (long long)1024 * 2304, 0, 0);

    // 5. h1 = relu(gate_in @ Wg1T^T + b_g1)   (BK=128: 18 K-steps)
    gemm_bf16<32, 64, 128><<<dim3(12, 64, 1), 256, 0, stream>>>(
        wsb + O_GATEIN, wsb + O_WG1T, wsb, nullptr, wsb + O_H1, b_g1, nullptr, nullptr,
        2048, 768, 2304, 2304, 2304, 0, 768, 0, 0, 0, 0, 2, 0);

    // 6. gate = sigmoid(h1 @ Wg2T^T + b_g2); fused = g*lin + (1-g)*win   (BK=128)
    gemm_bf16<32, 64, 128><<<dim3(12, 64, 1), 256, 0, stream>>>(
        wsb + O_H1, wsb + O_WG2T, wsb, nullptr, wsb + O_FUSED, b_g2, nullptr, nullptr,
        2048, 768, 768, 768, 768, 0, 768, 0, 0, 0, 0, 3, 2);

    // 7. out = fused @ WoutT^T + b_out + x   (BK=128)
    gemm_bf16<32, 64, 128><<<dim3(12, 64, 1), 256, 0, stream>>>(
        wsb + O_FUSED, wsb + O_WOUTT, wsb, (float*)d_out, nullptr, b_out, nullptr, x,
        2048, 768, 768, 768, 768, 768, 0, 0, 0, (long long)0, 0, 0, 0);
}

// Round 18
// 110.772 us; speedup vs baseline: 1.0627x; 1.0627x over previous
//
#include <hip/hip_runtime.h>
#include <math.h>

#define DD 768
#define SS 1024
#define BB 2
#define HH 12
#define DH 64

typedef __attribute__((ext_vector_type(8))) short bf16x8;
typedef __attribute__((ext_vector_type(8))) unsigned short u16x8;
typedef __attribute__((ext_vector_type(4))) float f32x4;

// ---- workspace layout (ushort units) ----
constexpr size_t O_GATEIN = 0;                                   // [2048][2304] bf16
constexpr size_t O_WPROJT = O_GATEIN + (size_t)2048 * 2304;      // [4608][768]
constexpr size_t O_WG1T   = O_WPROJT + (size_t)4608 * 768;       // [768][2304]
constexpr size_t O_WG2T   = O_WG1T + (size_t)768 * 2304;         // [768][768]
constexpr size_t O_WOUTT  = O_WG2T + (size_t)768 * 768;          // [768][768]
constexpr size_t O_PROJ   = O_WOUTT + (size_t)768 * 768;         // [2048][4608] (regions 0,3,4 used)
constexpr size_t O_KFT    = O_PROJ + (size_t)2048 * 4608;        // [2][768][1024]
constexpr size_t O_VLT    = O_KFT + (size_t)2 * 768 * 1024;      // [2][768][1024]
constexpr size_t O_VOT    = O_VLT + (size_t)2 * 768 * 1024;      // [2][12][64][1024]
constexpr size_t O_KVT    = O_VOT + (size_t)2 * 768 * 1024;      // [2][768][768]
constexpr size_t O_H1     = O_KVT + (size_t)2 * 768 * 768;       // [2048][768]
constexpr size_t O_FUSED  = O_H1 + (size_t)2048 * 768;           // [2048][768]
constexpr size_t O_F32    = O_FUSED + (size_t)2048 * 768;        // f32 area

__device__ inline unsigned short f2bf(float f) {
    unsigned int u = __builtin_bit_cast(unsigned int, f);
    unsigned int r = (u + 0x7fffu + ((u >> 16) & 1u)) >> 16;
    return (unsigned short)r;
}
__device__ inline float bf2f(unsigned short h) {
    unsigned int u = ((unsigned int)h) << 16;
    return __builtin_bit_cast(float, u);
}
__device__ inline void gload16(const ushort* g, ushort* l) {
    __builtin_amdgcn_global_load_lds((const __attribute__((address_space(1))) void*)g,
                                     (__attribute__((address_space(3))) void*)l, 16, 0, 0);
}

// ---------------- prep: weight transposes + bias concat + LayerNorm (+kfsum zero) ----------------
struct PrepArgs {
    const float* src[11];
    unsigned long long dstOff[11];
    int ldo[11];
    const float* bsrc[6];
    float* bdst;
    const float* x;
    const float* gamma;
    const float* beta;
    float* kfsum;
};
__global__ __launch_bounds__(256) void prep_kernel(PrepArgs a, ushort* __restrict__ wsb) {
    __shared__ float t[32][33];
    __shared__ float ws1[4], ws2[4], mstat[2];
    int bid = blockIdx.x;
    int tid = threadIdx.x;
    if (bid < 6336) {
        int z = bid / 576;
        int rem = bid - z * 576;
        int r0 = (rem / 24) * 32, c0 = (rem % 24) * 32;
        const float* ip = a.src[z];
        ushort* op = wsb + a.dstOff[z];
        int ldo = a.ldo[z];
        int tx = tid & 31, ty = tid >> 5;
        #pragma unroll
        for (int i = 0; i < 32; i += 8) t[ty + i][tx] = ip[(size_t)(r0 + ty + i) * 768 + c0 + tx];
        __syncthreads();
        #pragma unroll
        for (int i = 0; i < 32; i += 8) op[(size_t)(c0 + ty + i) * ldo + r0 + tx] = f2bf(t[tx][ty + i]);
        return;
    }
    if (bid < 6354) {
        int i = (bid - 6336) * 256 + tid;
        if (i < 4608) a.bdst[i] = a.bsrc[i / 768][i % 768];
        return;
    }
    int row = bid - 6354;
    if (row == 0) {
        #pragma unroll
        for (int i = 0; i < 6; ++i) a.kfsum[tid + i * 256] = 0.f;
    }
    const float* xr = a.x + (size_t)row * DD;
    ushort* outr = wsb + O_GATEIN + (size_t)row * 2304 + 1536;
    float v[3];
    float s = 0.f, s2 = 0.f;
    #pragma unroll
    for (int r = 0; r < 3; ++r) {
        v[r] = xr[tid + r * 256];
        s += v[r];
        s2 += v[r] * v[r];
    }
    #pragma unroll
    for (int o = 32; o > 0; o >>= 1) {
        s  += __shfl_down(s, o);
        s2 += __shfl_down(s2, o);
    }
    int wid = tid >> 6, lane = tid & 63;
    if (lane == 0) { ws1[wid] = s; ws2[wid] = s2; }
    __syncthreads();
    if (tid == 0) {
        float aa = 0.f, b2 = 0.f;
        #pragma unroll
        for (int i = 0; i < 4; ++i) { aa += ws1[i]; b2 += ws2[i]; }
        float mean = aa / (float)DD;
        float var = b2 / (float)DD - mean * mean;
        mstat[0] = mean;
        mstat[1] = rsqrtf(var + 1e-5f);
    }
    __syncthreads();
    float mean = mstat[0], rstd = mstat[1];
    #pragma unroll
    for (int r = 0; r < 3; ++r) {
        int i = tid + r * 256;
        outr[i] = f2bf((v[r] - mean) * rstd * a.gamma[i] + a.beta[i]);
    }
}

// ---------------- MFMA bf16 GEMM device body ----------------
// Counted-vmcnt 2-phase pipeline: stage(kt+1); vmcnt(NLD); s_barrier; MFMA; s_barrier.
// T2 swizzle: TPR>=8 -> row&(TPR-1); TPR==4 -> (row>>1)&3.
// mode 0: plain; mode 1 (TM=64,TN=128): fused projection scatter (+kfsum atomics via rowdiv);
// mode 2: gate2+fuse.
template<int TM, int TN, int BK>
__device__ __forceinline__ void gemm_dev(
    ushort* lds, int bx, int by, int bz,
    const ushort* __restrict__ A, const ushort* __restrict__ B,
    ushort* __restrict__ wsb,
    float* __restrict__ Cf, ushort* __restrict__ Cb,
    const float* __restrict__ bias, const float* __restrict__ rowdiv,
    const float* __restrict__ addsrc,
    int M, int N, int K, int lda, int ldb, int ldcf, int ldcb,
    long long bA, long long bB, long long bCf, long long bCb,
    int act, int mode) {
    constexpr int MF = TM / 32;
    constexpr int NF = TN / 32;
    constexpr int TPR = BK / 8;              // threads per row (staging)
    constexpr int ROWS = 2048 / BK;          // rows per staging round
    constexpr int AR = TM * BK / 2048;       // A staging rounds
    constexpr int BR = TN * BK / 2048;       // B staging rounds
    constexpr int NLD = AR + BR;
    constexpr int ABUF = TM * BK;
    constexpr int BBUF = TN * BK;
    const int tid = threadIdx.x, wid = tid >> 6, lane = tid & 63;
    const int m0 = by * TM, n0 = bx * TN, z = bz;
    const ushort* Az = A + (size_t)z * bA;
    const ushort* Bz = B + (size_t)z * bB;
    const int trow = tid / TPR;
    const int ssel = (TPR >= 8) ? (trow & (TPR - 1)) : ((trow >> 1) & 3);
    const int scol = ((tid % TPR) ^ ssel) * 8;
    const int wm = wid >> 1, wn = wid & 1;
    const int fr = lane & 15, fq = lane >> 4;
    const int rsel = (TPR >= 8) ? (fr & (TPR - 1)) : ((fr >> 1) & 3);
    f32x4 acc[MF][NF];
    #pragma unroll
    for (int i = 0; i < MF; ++i)
        #pragma unroll
        for (int j = 0; j < NF; ++j) acc[i][j] = f32x4{0.f, 0.f, 0.f, 0.f};
    const int nkt = K / BK;

    auto stage = [&](int t) {
        const int k0 = t * BK;
        const int bsel = t & 1;
        #pragma unroll
        for (int i = 0; i < AR; ++i)
            gload16(Az + (size_t)(m0 + i * ROWS + trow) * lda + k0 + scol,
                    &lds[bsel * ABUF + i * 2048 + wid * 512]);
        #pragma unroll
        for (int i = 0; i < BR; ++i)
            gload16(Bz + (size_t)(n0 + i * ROWS + trow) * ldb + k0 + scol,
                    &lds[2 * ABUF + bsel * BBUF + i * 2048 + wid * 512]);
    };

    stage(0);
    for (int kt = 0; kt < nkt; ++kt) {
        if (kt + 1 < nkt) {
            stage(kt + 1);
            if constexpr (NLD == 3)      asm volatile("s_waitcnt vmcnt(3)" ::: "memory");
            else if constexpr (NLD == 4) asm volatile("s_waitcnt vmcnt(4)" ::: "memory");
            else if constexpr (NLD == 5) asm volatile("s_waitcnt vmcnt(5)" ::: "memory");
            else if constexpr (NLD == 6) asm volatile("s_waitcnt vmcnt(6)" ::: "memory");
            else                         asm volatile("s_waitcnt vmcnt(8)" ::: "memory");
        } else {
            asm volatile("s_waitcnt vmcnt(0)" ::: "memory");
        }
        __builtin_amdgcn_s_barrier();
        const ushort* As = &lds[(kt & 1) * ABUF];
        const ushort* Bs = &lds[2 * ABUF + (kt & 1) * BBUF];
        #pragma unroll
        for (int ks = 0; ks < BK / 32; ++ks) {
            const int ck = (((ks * 4 + fq) ^ rsel) << 3);
            bf16x8 af[MF], bfr[NF];
            #pragma unroll
            for (int mf = 0; mf < MF; ++mf)
                af[mf] = *(const bf16x8*)&As[(wm * (TM / 2) + mf * 16 + fr) * BK + ck];
            #pragma unroll
            for (int nf = 0; nf < NF; ++nf)
                bfr[nf] = *(const bf16x8*)&Bs[(wn * (TN / 2) + nf * 16 + fr) * BK + ck];
            #pragma unroll
            for (int mf = 0; mf < MF; ++mf)
                #pragma unroll
                for (int nf = 0; nf < NF; ++nf)
                    acc[mf][nf] = __builtin_amdgcn_mfma_f32_16x16x32_bf16(af[mf], bfr[nf], acc[mf][nf], 0, 0, 0);
        }
        asm volatile("" ::: "memory");
        __builtin_amdgcn_s_barrier();
    }

    if constexpr (TM == 64 && TN == 128) {
        if (mode == 1) {
            const int region = n0 / 768;
            const int ncol = n0 - region * 768;
            const int b = m0 >> 10, s0 = m0 & 1023;
            const bool transposed = (region == 1 || region == 2 || region == 5);
            if (!transposed) {
                // regions 0 (qf, elu+1), 3 (qo), 4 (ko): row-major into proj
                #pragma unroll
                for (int mf = 0; mf < MF; ++mf) {
                    #pragma unroll
                    for (int j = 0; j < 4; ++j) {
                        int m = m0 + wm * (TM / 2) + mf * 16 + fq * 4 + j;
                        #pragma unroll
                        for (int nf = 0; nf < NF; ++nf) {
                            int n = n0 + wn * (TN / 2) + nf * 16 + fr;
                            float t = acc[mf][nf][j] + bias[n];
                            if (region == 0) t = (t > 0.f) ? t + 1.f : expf(t);
                            wsb[O_PROJ + (size_t)m * 4608 + n] = f2bf(t);
                        }
                    }
                }
            } else {
                // regions 1 (kf, elu+1), 2 (vl), 5 (vo): transpose via LDS -> [d][s]
                float psum[NF];
                #pragma unroll
                for (int i = 0; i < NF; ++i) psum[i] = 0.f;
                #pragma unroll
                for (int mf = 0; mf < MF; ++mf) {
                    #pragma unroll
                    for (int nf = 0; nf < NF; ++nf) {
                        int d_l = wn * (TN / 2) + nf * 16 + fr;
                        float bs = bias[n0 + d_l];
                        #pragma unroll
                        for (int j = 0; j < 4; ++j) {
                            int s_l = wm * (TM / 2) + mf * 16 + fq * 4 + j;
                            float t = acc[mf][nf][j] + bs;
                            if (region == 1) { t = (t > 0.f) ? t + 1.f : expf(t); psum[nf] += t; }
                            lds[d_l * (TM + 8) + s_l] = f2bf(t);
                        }
                    }
                }
                if (region == 1 && rowdiv) {
                    // kfsum: reduce over fq group (lanes ^16, ^32), one atomic per (wave, nf, fr)
                    #pragma unroll
                    for (int nf = 0; nf < NF; ++nf) {
                        float s = psum[nf];
                        s += __shfl_xor(s, 16);
                        s += __shfl_xor(s, 32);
                        if (fq == 0)
                            atomicAdd((float*)rowdiv + b * 768 + ncol + wn * (TN / 2) + nf * 16 + fr, s);
                    }
                }
                __syncthreads();
                size_t dstT = (region == 1) ? O_KFT : (region == 2) ? O_VLT : O_VOT;
                // TN rows x TM cols, u16x8 stores: TM/8 threads per row
                #pragma unroll
                for (int dd = 0; dd < (TN * TM / 8) / 256; ++dd) {
                    int d_l = dd * (256 / (TM / 8)) + tid / (TM / 8);
                    int sc8 = (tid % (TM / 8)) * 8;
                    u16x8 v = *(const u16x8*)&lds[d_l * (TM + 8) + sc8];
                    *(u16x8*)&wsb[dstT + (size_t)(b * 768 + ncol + d_l) * 1024 + s0 + sc8] = v;
                }
            }
            return;
        }
    }

    float* cfz = Cf ? Cf + (size_t)z * bCf : nullptr;
    ushort* cbz = Cb ? Cb + (size_t)z * bCb : nullptr;
    #pragma unroll
    for (int mf = 0; mf < MF; ++mf) {
        #pragma unroll
        for (int j = 0; j < 4; ++j) {
            int m = m0 + wm * (TM / 2) + mf * 16 + fq * 4 + j;
            float rd = rowdiv ? 1.f / (rowdiv[(size_t)z * M + m] + 1e-6f) : 1.f;
            #pragma unroll
            for (int nf = 0; nf < NF; ++nf) {
                int n = n0 + wn * (TN / 2) + nf * 16 + fr;
                float v = acc[mf][nf][j];
                if (bias) v += bias[n];
                v *= rd;
                if (act == 1) v = (v > 0.f) ? v + 1.f : expf(v);
                else if (act == 2) v = fmaxf(v, 0.f);
                else if (act == 3) v = 1.f / (1.f + expf(-v));
                if (mode == 2) {
                    float lin = bf2f(wsb[O_GATEIN + (size_t)m * 2304 + n]);
                    float win = bf2f(wsb[O_GATEIN + (size_t)m * 2304 + 768 + n]);
                    v = v * lin + (1.f - v) * win;
                }
                if (addsrc) v += addsrc[(size_t)m * ldcf + n];
                if (cfz) cfz[(size_t)m * ldcf + n] = v;
                if (cbz) cbz[(size_t)m * ldcb + n] = f2bf(v);
            }
        }
    }
}

template<int TM, int TN, int BK>
__global__ __launch_bounds__(256) void gemm_bf16(
    const ushort* __restrict__ A, const ushort* __restrict__ B,
    ushort* __restrict__ wsb,
    float* __restrict__ Cf, ushort* __restrict__ Cb,
    const float* __restrict__ bias, const float* __restrict__ rowdiv,
    const float* __restrict__ addsrc,
    int M, int N, int K, int lda, int ldb, int ldcf, int ldcb,
    long long bA, long long bB, long long bCf, long long bCb,
    int act, int mode) {
    constexpr int PIPE = 2 * TM * BK + 2 * TN * BK;
    constexpr int EPIL = (TM == 64 && TN == 128) ? 128 * (TM + 8) : 0;
    constexpr int LDSE = (PIPE > EPIL) ? PIPE : EPIL;
    __shared__ __align__(16) ushort lds[LDSE];
    // T1 XCD swizzle (bijective; all grids %8==0)
    int nwg = gridDim.x * gridDim.y;
    int flat = blockIdx.y * gridDim.x + blockIdx.x;
    int q = nwg >> 3;
    int nf = (flat & 7) * q + (flat >> 3);
    int bx = nf / gridDim.y;
    int by = nf % gridDim.y;
    gemm_dev<TM, TN, BK>(lds, bx, by, blockIdx.z, A, B, wsb, Cf, Cb,
                         bias, rowdiv, addsrc, M, N, K, lda, ldb, ldcf, ldcb,
                         bA, bB, bCf, bCb, act, mode);
}

// ---------------- merged kvT GEMM + windowed attention + normalizer ----------------
__global__ __launch_bounds__(256) void kv_attn(ushort* __restrict__ wsb,
                                               const float* __restrict__ kfsum,
                                               float* __restrict__ nrm) {
    __shared__ __align__(16) ushort lds[2 * 32 * 64 + 2 * 128 * 64];   // 20480 ushorts
    int bid = blockIdx.x;
    int tid = threadIdx.x;
    if (bid < 288) {
        int bx = bid % 6, by = (bid / 6) % 24, bz = bid / 144;
        gemm_dev<32, 128, 64>(lds, bx, by, bz,
            wsb + O_VLT, wsb + O_KFT, wsb, nullptr, wsb + O_KVT,
            nullptr, nullptr, nullptr,
            768, 768, 1024, 1024, 1024, 0, 768,
            (long long)768 * 1024, (long long)768 * 1024, 0, (long long)768 * 768, 0, 0);
        return;
    }
    if (bid >= 672) {
        int r = tid >> 3, p = tid & 7;
        int row = (bid - 672) * 32 + r;
        int b = row >> 10;
        const ushort* qrow = wsb + O_PROJ + (size_t)row * 4608 + p * 96;
        const float* kb = kfsum + b * 768 + p * 96;
        float s = 0.f;
        #pragma unroll
        for (int i = 0; i < 96; i += 8) {
            u16x8 v = *(const u16x8*)&qrow[i];
            #pragma unroll
            for (int j = 0; j < 8; ++j) s += bf2f(v[j]) * kb[i + j];
        }
        s += __shfl_xor(s, 1);
        s += __shfl_xor(s, 2);
        s += __shfl_xor(s, 4);
        if (p == 0) nrm[row] = s;
        return;
    }
    int a = bid - 288;
    int qx = a % 16, h = (a / 16) % 12, b = a / 192;
    ushort* Ps = lds;
    int wq = tid >> 6, lane = tid & 63;
    int fq = lane >> 4, fr = lane & 15;
    int q0 = qx * 64;
    const ushort* Pb = wsb + O_PROJ + (size_t)(b * SS) * 4608;
    const ushort* Vb = wsb + O_VOT + (size_t)(b * 768 + h * 64) * 1024;
    const int qoff = 2304 + h * 64, koff = 3072 + h * 64;

    int qrow = q0 + wq * 16 + fr;
    bf16x8 aq0 = *(const bf16x8*)&Pb[(size_t)qrow * 4608 + qoff + fq * 8];
    bf16x8 aq1 = *(const bf16x8*)&Pb[(size_t)qrow * 4608 + qoff + 32 + fq * 8];

    f32x4 sc[8];
    #pragma unroll
    for (int nf = 0; nf < 8; ++nf) sc[nf] = f32x4{0.f, 0.f, 0.f, 0.f};
    #pragma unroll
    for (int nf = 0; nf < 8; ++nf) {
        int kr = q0 - 32 + nf * 16 + fr;
        int kc = kr < 0 ? 0 : (kr > 1023 ? 1023 : kr);
        bf16x8 bk0 = *(const bf16x8*)&Pb[(size_t)kc * 4608 + koff + fq * 8];
        bf16x8 bk1 = *(const bf16x8*)&Pb[(size_t)kc * 4608 + koff + 32 + fq * 8];
        sc[nf] = __builtin_amdgcn_mfma_f32_16x16x32_bf16(aq0, bk0, sc[nf], 0, 0, 0);
        sc[nf] = __builtin_amdgcn_mfma_f32_16x16x32_bf16(aq1, bk1, sc[nf], 0, 0, 0);
    }

    float p[8][4];
    float inv[4];
    #pragma unroll
    for (int j = 0; j < 4; ++j) {
        int qt = wq * 16 + fq * 4 + j;
        float sv[8];
        float mx = -1e30f;
        #pragma unroll
        for (int nf = 0; nf < 8; ++nf) {
            int c = nf * 16 + fr;
            int kg = q0 - 32 + c;
            bool val = (c >= qt) && (c <= qt + 64) && (kg >= 0) && (kg < SS);
            float t = sc[nf][j] * 0.125f;
            sv[nf] = val ? t : -1e30f;
            mx = fmaxf(mx, sv[nf]);
        }
        mx = fmaxf(mx, __shfl_xor(mx, 1));
        mx = fmaxf(mx, __shfl_xor(mx, 2));
        mx = fmaxf(mx, __shfl_xor(mx, 4));
        mx = fmaxf(mx, __shfl_xor(mx, 8));
        float dn = 0.f;
        #pragma unroll
        for (int nf = 0; nf < 8; ++nf) {
            float e = expf(sv[nf] - mx);
            p[nf][j] = e;
            dn += e;
        }
        dn += __shfl_xor(dn, 1);
        dn += __shfl_xor(dn, 2);
        dn += __shfl_xor(dn, 4);
        dn += __shfl_xor(dn, 8);
        inv[j] = 1.f / dn;
    }

    #pragma unroll
    for (int nf = 0; nf < 8; ++nf) {
        int chunk = nf * 2 + (fr >> 3);
        #pragma unroll
        for (int j = 0; j < 4; ++j) {
            int r = fq * 4 + j;
            Ps[wq * 2048 + r * 128 + ((chunk ^ r) * 8) + (fr & 7)] = f2bf(p[nf][j] * inv[j]);
        }
    }
    __syncthreads();

    f32x4 oa[4];
    #pragma unroll
    for (int nf = 0; nf < 4; ++nf) oa[nf] = f32x4{0.f, 0.f, 0.f, 0.f};
    #pragma unroll
    for (int ks = 0; ks < 4; ++ks) {
        bf16x8 pa = *(const bf16x8*)&Ps[wq * 2048 + fr * 128 + (((ks * 4 + fq) ^ fr) * 8)];
        #pragma unroll
        for (int nf = 0; nf < 4; ++nf) {
            int dr = nf * 16 + fr;
            const ushort* vp = Vb + (ptrdiff_t)dr * 1024 + (q0 - 32 + ks * 32 + fq * 8);
            bf16x8 bv = *(const bf16x8*)vp;
            oa[nf] = __builtin_amdgcn_mfma_f32_16x16x32_bf16(pa, bv, oa[nf], 0, 0, 0);
        }
    }

    #pragma unroll
    for (int nf = 0; nf < 4; ++nf) {
        int d = nf * 16 + fr;
        #pragma unroll
        for (int j = 0; j < 4; ++j) {
            int q = q0 + wq * 16 + fq * 4 + j;
            wsb[O_GATEIN + (size_t)(b * SS + q) * 2304 + 768 + h * 64 + d] = f2bf(oa[nf][j]);
        }
    }
}

extern "C" void kernel_launch(void* const* d_in, const int* in_sizes, int n_in,
                              void* d_out, int out_size, void* d_ws, size_t ws_size,
                              hipStream_t stream) {
    const float* x      = (const float*)d_in[0];
    const float* W_q    = (const float*)d_in[1];
    const float* b_q    = (const float*)d_in[2];
    const float* W_k    = (const float*)d_in[3];
    const float* b_k    = (const float*)d_in[4];
    const float* W_v    = (const float*)d_in[5];
    const float* b_v    = (const float*)d_in[6];
    const float* W_ql   = (const float*)d_in[7];
    const float* b_ql   = (const float*)d_in[8];
    const float* W_kl   = (const float*)d_in[9];
    const float* b_kl   = (const float*)d_in[10];
    const float* W_vl   = (const float*)d_in[11];
    const float* b_vl   = (const float*)d_in[12];
    const float* W_out  = (const float*)d_in[13];
    const float* b_out  = (const float*)d_in[14];
    const float* W_g1   = (const float*)d_in[15];
    const float* b_g1   = (const float*)d_in[16];
    const float* W_g2   = (const float*)d_in[17];
    const float* b_g2   = (const float*)d_in[18];
    const float* gamma1 = (const float*)d_in[19];
    const float* beta1  = (const float*)d_in[20];

    ushort* wsb = (ushort*)d_ws;
    float* f32a = (float*)(wsb + O_F32);
    float* bias_cat = f32a;            // 4608
    float* kfsum    = f32a + 4608;     // 1536
    float* nrm      = kfsum + 1536;    // 2048

    const long long W2 = (long long)768 * 768;

    // 1. prep: weight transposes + bias concat + LayerNorm (+ kfsum zero)
    PrepArgs pa;
    const float* wsrc[6] = {W_q, W_k, W_v, W_ql, W_kl, W_vl};
    for (int i = 0; i < 6; ++i) { pa.src[i] = wsrc[i]; pa.dstOff[i] = O_WPROJT + i * W2; pa.ldo[i] = 768; }
    for (int i = 0; i < 3; ++i) { pa.src[6 + i] = W_g1 + (size_t)i * 768 * 768; pa.dstOff[6 + i] = O_WG1T + i * 768; pa.ldo[6 + i] = 2304; }
    pa.src[9] = W_g2;  pa.dstOff[9] = O_WG2T;  pa.ldo[9] = 768;
    pa.src[10] = W_out; pa.dstOff[10] = O_WOUTT; pa.ldo[10] = 768;
    const float* bsrc[6] = {b_q, b_k, b_v, b_ql, b_kl, b_vl};
    for (int i = 0; i < 6; ++i) pa.bsrc[i] = bsrc[i];
    pa.bdst = bias_cat;
    pa.x = x; pa.gamma = gamma1; pa.beta = beta1;
    pa.kfsum = kfsum;
    prep_kernel<<<dim3(8402), 256, 0, stream>>>(pa, wsb);

    // 2. fused 6-way projection (mode 1; TM=64 TN=128 BK=64 -> 1152 blocks, 3/CU)
    gemm_bf16<64, 128, 64><<<dim3(36, 32, 1), 256, 0, stream>>>(
        wsb + O_GATEIN + 1536, wsb + O_WPROJT, wsb, nullptr, nullptr, bias_cat, kfsum, nullptr,
        2048, 4608, 768, 2304, 768, 0, 0, 0, 0, 0, 0, 0, 1);

    // 3. kvT GEMM + windowed attention + normalizer (merged full-machine pass)
    kv_attn<<<dim3(736), 256, 0, stream>>>(wsb, kfsum, nrm);

    // 4. lin = (qf @ kvT^T)/nrm -> gate_in slice 0   (BK=64, round-15 proven)
    gemm_bf16<32, 64, 64><<<dim3(12, 32, 2), 256, 0, stream>>>(
        wsb + O_PROJ, wsb + O_KVT, wsb, nullptr, wsb + O_GATEIN, nullptr, nrm, nullptr,
        1024, 768, 768, 4608, 768, 0, 2304,
        (long long)1024 * 4608, W2, 0, (long long)1024 * 2304, 0, 0);

    // 5. h1 = relu(gate_in @ Wg1T^T + b_g1)   (BK=64)
    gemm_bf16<32, 64, 64><<<dim3(12, 64, 1), 256, 0, stream>>>(
        wsb + O_GATEIN, wsb + O_WG1T, wsb, nullptr, wsb + O_H1, b_g1, nullptr, nullptr,
        2048, 768, 2304, 2304, 2304, 0, 768, 0, 0, 0, 0, 2, 0);

    // 6. gate = sigmoid(h1 @ Wg2T^T + b_g2); fused = g*lin + (1-g)*win   (BK=64)
    gemm_bf16<32, 64, 64><<<dim3(12, 64, 1), 256, 0, stream>>>(
        wsb + O_H1, wsb + O_WG2T, wsb, nullptr, wsb + O_FUSED, b_g2, nullptr, nullptr,
        2048, 768, 768, 768, 768, 0, 768, 0, 0, 0, 0, 3, 2);

    // 7. out = fused @ WoutT^T + b_out + x   (BK=64)
    gemm_bf16<32, 64, 64><<<dim3(12, 64, 1), 256, 0, stream>>>(
        wsb + O_FUSED, wsb + O_WOUTT, wsb, (float*)d_out, nullptr, b_out, nullptr, x,
        2048, 768, 768, 768, 768, 768, 0, 0, 0, (long long)0, 0, 0, 0);
}

// Round 19
// 109.696 us; speedup vs baseline: 1.0731x; 1.0098x over previous
//
#include <hip/hip_runtime.h>
#include <math.h>

#define DD 768
#define SS 1024
#define BB 2
#define HH 12
#define DH 64

typedef __attribute__((ext_vector_type(8))) short bf16x8;
typedef __attribute__((ext_vector_type(8))) unsigned short u16x8;
typedef __attribute__((ext_vector_type(4))) float f32x4;

// ---- workspace layout (ushort units) ----
constexpr size_t O_GATEIN = 0;                                   // [2048][2304] bf16
constexpr size_t O_WPROJT = O_GATEIN + (size_t)2048 * 2304;      // [4608][768]
constexpr size_t O_WG1T   = O_WPROJT + (size_t)4608 * 768;       // [768][2304]
constexpr size_t O_WG2T   = O_WG1T + (size_t)768 * 2304;         // [768][768]
constexpr size_t O_WOUTT  = O_WG2T + (size_t)768 * 768;          // [768][768]
constexpr size_t O_PROJ   = O_WOUTT + (size_t)768 * 768;         // [2048][4608] (regions 0,3,4 used)
constexpr size_t O_KFT    = O_PROJ + (size_t)2048 * 4608;        // [2][768][1024]
constexpr size_t O_VLT    = O_KFT + (size_t)2 * 768 * 1024;      // [2][768][1024]
constexpr size_t O_VOT    = O_VLT + (size_t)2 * 768 * 1024;      // [2][12][64][1024]
constexpr size_t O_KVT    = O_VOT + (size_t)2 * 768 * 1024;      // [2][768][768]
constexpr size_t O_H1     = O_KVT + (size_t)2 * 768 * 768;       // [2048][768]
constexpr size_t O_FUSED  = O_H1 + (size_t)2048 * 768;           // [2048][768]
constexpr size_t O_F32    = O_FUSED + (size_t)2048 * 768;        // f32 area

__device__ inline unsigned short f2bf(float f) {
    unsigned int u = __builtin_bit_cast(unsigned int, f);
    unsigned int r = (u + 0x7fffu + ((u >> 16) & 1u)) >> 16;
    return (unsigned short)r;
}
__device__ inline float bf2f(unsigned short h) {
    unsigned int u = ((unsigned int)h) << 16;
    return __builtin_bit_cast(float, u);
}
__device__ inline void gload16(const ushort* g, ushort* l) {
    __builtin_amdgcn_global_load_lds((const __attribute__((address_space(1))) void*)g,
                                     (__attribute__((address_space(3))) void*)l, 16, 0, 0);
}

// ---------------- prep: weight transposes (64x32 tiles) + bias concat + LayerNorm (+kfsum zero) ----------------
// blocks [0,3168): transpose 11 matrices (288 blocks each, 64 rows x 32 cols per tile)
// blocks [3168,3186): bias concat
// blocks [3186,5234): LayerNorm rows
struct PrepArgs {
    const float* src[11];
    unsigned long long dstOff[11];
    int ldo[11];
    const float* bsrc[6];
    float* bdst;
    const float* x;
    const float* gamma;
    const float* beta;
    float* kfsum;
};
__global__ __launch_bounds__(256) void prep_kernel(PrepArgs a, ushort* __restrict__ wsb) {
    __shared__ float t[64][33];
    __shared__ float ws1[4], ws2[4], mstat[2];
    int bid = blockIdx.x;
    int tid = threadIdx.x;
    if (bid < 3168) {
        int z = bid / 288;
        int rem = bid - z * 288;
        int r0 = (rem / 24) * 64, c0 = (rem % 24) * 32;
        const float* ip = a.src[z];
        ushort* op = wsb + a.dstOff[z];
        int ldo = a.ldo[z];
        // load 64x32 f32: full 128B rows
        #pragma unroll
        for (int k = 0; k < 8; ++k) {
            int e = k * 256 + tid;
            int row = e >> 5, col = e & 31;
            t[row][col] = ip[(size_t)(r0 + row) * 768 + c0 + col];
        }
        __syncthreads();
        // store 32 output rows x 64 ushorts: full 128B rows
        #pragma unroll
        for (int k = 0; k < 8; ++k) {
            int w = k * 256 + tid;
            int cc = w >> 6, rr = w & 63;
            op[(size_t)(c0 + cc) * ldo + r0 + rr] = f2bf(t[rr][cc]);
        }
        return;
    }
    if (bid < 3186) {
        int i = (bid - 3168) * 256 + tid;
        if (i < 4608) a.bdst[i] = a.bsrc[i / 768][i % 768];
        return;
    }
    int row = bid - 3186;
    if (row == 0) {
        #pragma unroll
        for (int i = 0; i < 6; ++i) a.kfsum[tid + i * 256] = 0.f;
    }
    const float* xr = a.x + (size_t)row * DD;
    ushort* outr = wsb + O_GATEIN + (size_t)row * 2304 + 1536;
    float v[3];
    float s = 0.f, s2 = 0.f;
    #pragma unroll
    for (int r = 0; r < 3; ++r) {
        v[r] = xr[tid + r * 256];
        s += v[r];
        s2 += v[r] * v[r];
    }
    #pragma unroll
    for (int o = 32; o > 0; o >>= 1) {
        s  += __shfl_down(s, o);
        s2 += __shfl_down(s2, o);
    }
    int wid = tid >> 6, lane = tid & 63;
    if (lane == 0) { ws1[wid] = s; ws2[wid] = s2; }
    __syncthreads();
    if (tid == 0) {
        float aa = 0.f, b2 = 0.f;
        #pragma unroll
        for (int i = 0; i < 4; ++i) { aa += ws1[i]; b2 += ws2[i]; }
        float mean = aa / (float)DD;
        float var = b2 / (float)DD - mean * mean;
        mstat[0] = mean;
        mstat[1] = rsqrtf(var + 1e-5f);
    }
    __syncthreads();
    float mean = mstat[0], rstd = mstat[1];
    #pragma unroll
    for (int r = 0; r < 3; ++r) {
        int i = tid + r * 256;
        outr[i] = f2bf((v[r] - mean) * rstd * a.gamma[i] + a.beta[i]);
    }
}

// ---------------- MFMA bf16 GEMM device body ----------------
// Counted-vmcnt 2-phase pipeline: stage(kt+1); vmcnt(NLD); s_barrier; MFMA; s_barrier.
// T2 swizzle: TPR>=8 -> row&(TPR-1); TPR==4 -> (row>>1)&3.
// mode 0: plain; mode 1 (TM=64,TN=128): fused projection scatter (+kfsum atomics via rowdiv);
// mode 2: gate2+fuse.
template<int TM, int TN, int BK>
__device__ __forceinline__ void gemm_dev(
    ushort* lds, int bx, int by, int bz,
    const ushort* __restrict__ A, const ushort* __restrict__ B,
    ushort* __restrict__ wsb,
    float* __restrict__ Cf, ushort* __restrict__ Cb,
    const float* __restrict__ bias, const float* __restrict__ rowdiv,
    const float* __restrict__ addsrc,
    int M, int N, int K, int lda, int ldb, int ldcf, int ldcb,
    long long bA, long long bB, long long bCf, long long bCb,
    int act, int mode) {
    constexpr int MF = TM / 32;
    constexpr int NF = TN / 32;
    constexpr int TPR = BK / 8;              // threads per row (staging)
    constexpr int ROWS = 2048 / BK;          // rows per staging round
    constexpr int AR = TM * BK / 2048;       // A staging rounds
    constexpr int BR = TN * BK / 2048;       // B staging rounds
    constexpr int NLD = AR + BR;
    constexpr int ABUF = TM * BK;
    constexpr int BBUF = TN * BK;
    const int tid = threadIdx.x, wid = tid >> 6, lane = tid & 63;
    const int m0 = by * TM, n0 = bx * TN, z = bz;
    const ushort* Az = A + (size_t)z * bA;
    const ushort* Bz = B + (size_t)z * bB;
    const int trow = tid / TPR;
    const int ssel = (TPR >= 8) ? (trow & (TPR - 1)) : ((trow >> 1) & 3);
    const int scol = ((tid % TPR) ^ ssel) * 8;
    const int wm = wid >> 1, wn = wid & 1;
    const int fr = lane & 15, fq = lane >> 4;
    const int rsel = (TPR >= 8) ? (fr & (TPR - 1)) : ((fr >> 1) & 3);
    f32x4 acc[MF][NF];
    #pragma unroll
    for (int i = 0; i < MF; ++i)
        #pragma unroll
        for (int j = 0; j < NF; ++j) acc[i][j] = f32x4{0.f, 0.f, 0.f, 0.f};
    const int nkt = K / BK;

    auto stage = [&](int t) {
        const int k0 = t * BK;
        const int bsel = t & 1;
        #pragma unroll
        for (int i = 0; i < AR; ++i)
            gload16(Az + (size_t)(m0 + i * ROWS + trow) * lda + k0 + scol,
                    &lds[bsel * ABUF + i * 2048 + wid * 512]);
        #pragma unroll
        for (int i = 0; i < BR; ++i)
            gload16(Bz + (size_t)(n0 + i * ROWS + trow) * ldb + k0 + scol,
                    &lds[2 * ABUF + bsel * BBUF + i * 2048 + wid * 512]);
    };

    stage(0);
    for (int kt = 0; kt < nkt; ++kt) {
        if (kt + 1 < nkt) {
            stage(kt + 1);
            if constexpr (NLD == 3)      asm volatile("s_waitcnt vmcnt(3)" ::: "memory");
            else if constexpr (NLD == 4) asm volatile("s_waitcnt vmcnt(4)" ::: "memory");
            else if constexpr (NLD == 5) asm volatile("s_waitcnt vmcnt(5)" ::: "memory");
            else if constexpr (NLD == 6) asm volatile("s_waitcnt vmcnt(6)" ::: "memory");
            else                         asm volatile("s_waitcnt vmcnt(8)" ::: "memory");
        } else {
            asm volatile("s_waitcnt vmcnt(0)" ::: "memory");
        }
        __builtin_amdgcn_s_barrier();
        const ushort* As = &lds[(kt & 1) * ABUF];
        const ushort* Bs = &lds[2 * ABUF + (kt & 1) * BBUF];
        #pragma unroll
        for (int ks = 0; ks < BK / 32; ++ks) {
            const int ck = (((ks * 4 + fq) ^ rsel) << 3);
            bf16x8 af[MF], bfr[NF];
            #pragma unroll
            for (int mf = 0; mf < MF; ++mf)
                af[mf] = *(const bf16x8*)&As[(wm * (TM / 2) + mf * 16 + fr) * BK + ck];
            #pragma unroll
            for (int nf = 0; nf < NF; ++nf)
                bfr[nf] = *(const bf16x8*)&Bs[(wn * (TN / 2) + nf * 16 + fr) * BK + ck];
            #pragma unroll
            for (int mf = 0; mf < MF; ++mf)
                #pragma unroll
                for (int nf = 0; nf < NF; ++nf)
                    acc[mf][nf] = __builtin_amdgcn_mfma_f32_16x16x32_bf16(af[mf], bfr[nf], acc[mf][nf], 0, 0, 0);
        }
        asm volatile("" ::: "memory");
        __builtin_amdgcn_s_barrier();
    }

    if constexpr (TM == 64 && TN == 128) {
        if (mode == 1) {
            const int region = n0 / 768;
            const int ncol = n0 - region * 768;
            const int b = m0 >> 10, s0 = m0 & 1023;
            const bool transposed = (region == 1 || region == 2 || region == 5);
            if (!transposed) {
                // regions 0 (qf, elu+1), 3 (qo), 4 (ko): row-major into proj
                #pragma unroll
                for (int mf = 0; mf < MF; ++mf) {
                    #pragma unroll
                    for (int j = 0; j < 4; ++j) {
                        int m = m0 + wm * (TM / 2) + mf * 16 + fq * 4 + j;
                        #pragma unroll
                        for (int nf = 0; nf < NF; ++nf) {
                            int n = n0 + wn * (TN / 2) + nf * 16 + fr;
                            float t = acc[mf][nf][j] + bias[n];
                            if (region == 0) t = (t > 0.f) ? t + 1.f : expf(t);
                            wsb[O_PROJ + (size_t)m * 4608 + n] = f2bf(t);
                        }
                    }
                }
            } else {
                // regions 1 (kf, elu+1), 2 (vl), 5 (vo): transpose via LDS -> [d][s]
                float psum[NF];
                #pragma unroll
                for (int i = 0; i < NF; ++i) psum[i] = 0.f;
                #pragma unroll
                for (int mf = 0; mf < MF; ++mf) {
                    #pragma unroll
                    for (int nf = 0; nf < NF; ++nf) {
                        int d_l = wn * (TN / 2) + nf * 16 + fr;
                        float bs = bias[n0 + d_l];
                        #pragma unroll
                        for (int j = 0; j < 4; ++j) {
                            int s_l = wm * (TM / 2) + mf * 16 + fq * 4 + j;
                            float t = acc[mf][nf][j] + bs;
                            if (region == 1) { t = (t > 0.f) ? t + 1.f : expf(t); psum[nf] += t; }
                            lds[d_l * (TM + 8) + s_l] = f2bf(t);
                        }
                    }
                }
                if (region == 1 && rowdiv) {
                    // kfsum: reduce over fq group (lanes ^16, ^32), one atomic per (wave, nf, fr)
                    #pragma unroll
                    for (int nf = 0; nf < NF; ++nf) {
                        float s = psum[nf];
                        s += __shfl_xor(s, 16);
                        s += __shfl_xor(s, 32);
                        if (fq == 0)
                            atomicAdd((float*)rowdiv + b * 768 + ncol + wn * (TN / 2) + nf * 16 + fr, s);
                    }
                }
                __syncthreads();
                size_t dstT = (region == 1) ? O_KFT : (region == 2) ? O_VLT : O_VOT;
                // TN rows x TM cols, u16x8 stores: TM/8 threads per row
                #pragma unroll
                for (int dd = 0; dd < (TN * TM / 8) / 256; ++dd) {
                    int d_l = dd * (256 / (TM / 8)) + tid / (TM / 8);
                    int sc8 = (tid % (TM / 8)) * 8;
                    u16x8 v = *(const u16x8*)&lds[d_l * (TM + 8) + sc8];
                    *(u16x8*)&wsb[dstT + (size_t)(b * 768 + ncol + d_l) * 1024 + s0 + sc8] = v;
                }
            }
            return;
        }
    }

    float* cfz = Cf ? Cf + (size_t)z * bCf : nullptr;
    ushort* cbz = Cb ? Cb + (size_t)z * bCb : nullptr;
    #pragma unroll
    for (int mf = 0; mf < MF; ++mf) {
        #pragma unroll
        for (int j = 0; j < 4; ++j) {
            int m = m0 + wm * (TM / 2) + mf * 16 + fq * 4 + j;
            float rd = rowdiv ? 1.f / (rowdiv[(size_t)z * M + m] + 1e-6f) : 1.f;
            #pragma unroll
            for (int nf = 0; nf < NF; ++nf) {
                int n = n0 + wn * (TN / 2) + nf * 16 + fr;
                float v = acc[mf][nf][j];
                if (bias) v += bias[n];
                v *= rd;
                if (act == 1) v = (v > 0.f) ? v + 1.f : expf(v);
                else if (act == 2) v = fmaxf(v, 0.f);
                else if (act == 3) v = 1.f / (1.f + expf(-v));
                if (mode == 2) {
                    float lin = bf2f(wsb[O_GATEIN + (size_t)m * 2304 + n]);
                    float win = bf2f(wsb[O_GATEIN + (size_t)m * 2304 + 768 + n]);
                    v = v * lin + (1.f - v) * win;
                }
                if (addsrc) v += addsrc[(size_t)m * ldcf + n];
                if (cfz) cfz[(size_t)m * ldcf + n] = v;
                if (cbz) cbz[(size_t)m * ldcb + n] = f2bf(v);
            }
        }
    }
}

template<int TM, int TN, int BK>
__global__ __launch_bounds__(256) void gemm_bf16(
    const ushort* __restrict__ A, const ushort* __restrict__ B,
    ushort* __restrict__ wsb,
    float* __restrict__ Cf, ushort* __restrict__ Cb,
    const float* __restrict__ bias, const float* __restrict__ rowdiv,
    const float* __restrict__ addsrc,
    int M, int N, int K, int lda, int ldb, int ldcf, int ldcb,
    long long bA, long long bB, long long bCf, long long bCb,
    int act, int mode) {
    constexpr int PIPE = 2 * TM * BK + 2 * TN * BK;
    constexpr int EPIL = (TM == 64 && TN == 128) ? 128 * (TM + 8) : 0;
    constexpr int LDSE = (PIPE > EPIL) ? PIPE : EPIL;
    __shared__ __align__(16) ushort lds[LDSE];
    // T1 XCD swizzle (bijective; all grids %8==0)
    int nwg = gridDim.x * gridDim.y;
    int flat = blockIdx.y * gridDim.x + blockIdx.x;
    int q = nwg >> 3;
    int nf = (flat & 7) * q + (flat >> 3);
    int bx = nf / gridDim.y;
    int by = nf % gridDim.y;
    gemm_dev<TM, TN, BK>(lds, bx, by, blockIdx.z, A, B, wsb, Cf, Cb,
                         bias, rowdiv, addsrc, M, N, K, lda, ldb, ldcf, ldcb,
                         bA, bB, bCf, bCb, act, mode);
}

// ---------------- merged kvT GEMM + windowed attention + normalizer ----------------
__global__ __launch_bounds__(256) void kv_attn(ushort* __restrict__ wsb,
                                               const float* __restrict__ kfsum,
                                               float* __restrict__ nrm) {
    __shared__ __align__(16) ushort lds[2 * 32 * 64 + 2 * 128 * 64];   // 20480 ushorts
    int bid = blockIdx.x;
    int tid = threadIdx.x;
    if (bid < 288) {
        int bx = bid % 6, by = (bid / 6) % 24, bz = bid / 144;
        gemm_dev<32, 128, 64>(lds, bx, by, bz,
            wsb + O_VLT, wsb + O_KFT, wsb, nullptr, wsb + O_KVT,
            nullptr, nullptr, nullptr,
            768, 768, 1024, 1024, 1024, 0, 768,
            (long long)768 * 1024, (long long)768 * 1024, 0, (long long)768 * 768, 0, 0);
        return;
    }
    if (bid >= 672) {
        int r = tid >> 3, p = tid & 7;
        int row = (bid - 672) * 32 + r;
        int b = row >> 10;
        const ushort* qrow = wsb + O_PROJ + (size_t)row * 4608 + p * 96;
        const float* kb = kfsum + b * 768 + p * 96;
        float s = 0.f;
        #pragma unroll
        for (int i = 0; i < 96; i += 8) {
            u16x8 v = *(const u16x8*)&qrow[i];
            #pragma unroll
            for (int j = 0; j < 8; ++j) s += bf2f(v[j]) * kb[i + j];
        }
        s += __shfl_xor(s, 1);
        s += __shfl_xor(s, 2);
        s += __shfl_xor(s, 4);
        if (p == 0) nrm[row] = s;
        return;
    }
    int a = bid - 288;
    int qx = a % 16, h = (a / 16) % 12, b = a / 192;
    ushort* Ps = lds;
    int wq = tid >> 6, lane = tid & 63;
    int fq = lane >> 4, fr = lane & 15;
    int q0 = qx * 64;
    const ushort* Pb = wsb + O_PROJ + (size_t)(b * SS) * 4608;
    const ushort* Vb = wsb + O_VOT + (size_t)(b * 768 + h * 64) * 1024;
    const int qoff = 2304 + h * 64, koff = 3072 + h * 64;

    int qrow = q0 + wq * 16 + fr;
    bf16x8 aq0 = *(const bf16x8*)&Pb[(size_t)qrow * 4608 + qoff + fq * 8];
    bf16x8 aq1 = *(const bf16x8*)&Pb[(size_t)qrow * 4608 + qoff + 32 + fq * 8];

    f32x4 sc[8];
    #pragma unroll
    for (int nf = 0; nf < 8; ++nf) sc[nf] = f32x4{0.f, 0.f, 0.f, 0.f};
    #pragma unroll
    for (int nf = 0; nf < 8; ++nf) {
        int kr = q0 - 32 + nf * 16 + fr;
        int kc = kr < 0 ? 0 : (kr > 1023 ? 1023 : kr);
        bf16x8 bk0 = *(const bf16x8*)&Pb[(size_t)kc * 4608 + koff + fq * 8];
        bf16x8 bk1 = *(const bf16x8*)&Pb[(size_t)kc * 4608 + koff + 32 + fq * 8];
        sc[nf] = __builtin_amdgcn_mfma_f32_16x16x32_bf16(aq0, bk0, sc[nf], 0, 0, 0);
        sc[nf] = __builtin_amdgcn_mfma_f32_16x16x32_bf16(aq1, bk1, sc[nf], 0, 0, 0);
    }

    float p[8][4];
    float inv[4];
    #pragma unroll
    for (int j = 0; j < 4; ++j) {
        int qt = wq * 16 + fq * 4 + j;
        float sv[8];
        float mx = -1e30f;
        #pragma unroll
        for (int nf = 0; nf < 8; ++nf) {
            int c = nf * 16 + fr;
            int kg = q0 - 32 + c;
            bool val = (c >= qt) && (c <= qt + 64) && (kg >= 0) && (kg < SS);
            float t = sc[nf][j] * 0.125f;
            sv[nf] = val ? t : -1e30f;
            mx = fmaxf(mx, sv[nf]);
        }
        mx = fmaxf(mx, __shfl_xor(mx, 1));
        mx = fmaxf(mx, __shfl_xor(mx, 2));
        mx = fmaxf(mx, __shfl_xor(mx, 4));
        mx = fmaxf(mx, __shfl_xor(mx, 8));
        float dn = 0.f;
        #pragma unroll
        for (int nf = 0; nf < 8; ++nf) {
            float e = expf(sv[nf] - mx);
            p[nf][j] = e;
            dn += e;
        }
        dn += __shfl_xor(dn, 1);
        dn += __shfl_xor(dn, 2);
        dn += __shfl_xor(dn, 4);
        dn += __shfl_xor(dn, 8);
        inv[j] = 1.f / dn;
    }

    #pragma unroll
    for (int nf = 0; nf < 8; ++nf) {
        int chunk = nf * 2 + (fr >> 3);
        #pragma unroll
        for (int j = 0; j < 4; ++j) {
            int r = fq * 4 + j;
            Ps[wq * 2048 + r * 128 + ((chunk ^ r) * 8) + (fr & 7)] = f2bf(p[nf][j] * inv[j]);
        }
    }
    __syncthreads();

    f32x4 oa[4];
    #pragma unroll
    for (int nf = 0; nf < 4; ++nf) oa[nf] = f32x4{0.f, 0.f, 0.f, 0.f};
    #pragma unroll
    for (int ks = 0; ks < 4; ++ks) {
        bf16x8 pa = *(const bf16x8*)&Ps[wq * 2048 + fr * 128 + (((ks * 4 + fq) ^ fr) * 8)];
        #pragma unroll
        for (int nf = 0; nf < 4; ++nf) {
            int dr = nf * 16 + fr;
            const ushort* vp = Vb + (ptrdiff_t)dr * 1024 + (q0 - 32 + ks * 32 + fq * 8);
            bf16x8 bv = *(const bf16x8*)vp;
            oa[nf] = __builtin_amdgcn_mfma_f32_16x16x32_bf16(pa, bv, oa[nf], 0, 0, 0);
        }
    }

    #pragma unroll
    for (int nf = 0; nf < 4; ++nf) {
        int d = nf * 16 + fr;
        #pragma unroll
        for (int j = 0; j < 4; ++j) {
            int q = q0 + wq * 16 + fq * 4 + j;
            wsb[O_GATEIN + (size_t)(b * SS + q) * 2304 + 768 + h * 64 + d] = f2bf(oa[nf][j]);
        }
    }
}

extern "C" void kernel_launch(void* const* d_in, const int* in_sizes, int n_in,
                              void* d_out, int out_size, void* d_ws, size_t ws_size,
                              hipStream_t stream) {
    const float* x      = (const float*)d_in[0];
    const float* W_q    = (const float*)d_in[1];
    const float* b_q    = (const float*)d_in[2];
    const float* W_k    = (const float*)d_in[3];
    const float* b_k    = (const float*)d_in[4];
    const float* W_v    = (const float*)d_in[5];
    const float* b_v    = (const float*)d_in[6];
    const float* W_ql   = (const float*)d_in[7];
    const float* b_ql   = (const float*)d_in[8];
    const float* W_kl   = (const float*)d_in[9];
    const float* b_kl   = (const float*)d_in[10];
    const float* W_vl   = (const float*)d_in[11];
    const float* b_vl   = (const float*)d_in[12];
    const float* W_out  = (const float*)d_in[13];
    const float* b_out  = (const float*)d_in[14];
    const float* W_g1   = (const float*)d_in[15];
    const float* b_g1   = (const float*)d_in[16];
    const float* W_g2   = (const float*)d_in[17];
    const float* b_g2   = (const float*)d_in[18];
    const float* gamma1 = (const float*)d_in[19];
    const float* beta1  = (const float*)d_in[20];

    ushort* wsb = (ushort*)d_ws;
    float* f32a = (float*)(wsb + O_F32);
    float* bias_cat = f32a;            // 4608
    float* kfsum    = f32a + 4608;     // 1536
    float* nrm      = kfsum + 1536;    // 2048

    const long long W2 = (long long)768 * 768;

    // 1. prep: weight transposes (64x32 tiles) + bias concat + LayerNorm (+ kfsum zero)
    PrepArgs pa;
    const float* wsrc[6] = {W_q, W_k, W_v, W_ql, W_kl, W_vl};
    for (int i = 0; i < 6; ++i) { pa.src[i] = wsrc[i]; pa.dstOff[i] = O_WPROJT + i * W2; pa.ldo[i] = 768; }
    for (int i = 0; i < 3; ++i) { pa.src[6 + i] = W_g1 + (size_t)i * 768 * 768; pa.dstOff[6 + i] = O_WG1T + i * 768; pa.ldo[6 + i] = 2304; }
    pa.src[9] = W_g2;  pa.dstOff[9] = O_WG2T;  pa.ldo[9] = 768;
    pa.src[10] = W_out; pa.dstOff[10] = O_WOUTT; pa.ldo[10] = 768;
    const float* bsrc[6] = {b_q, b_k, b_v, b_ql, b_kl, b_vl};
    for (int i = 0; i < 6; ++i) pa.bsrc[i] = bsrc[i];
    pa.bdst = bias_cat;
    pa.x = x; pa.gamma = gamma1; pa.beta = beta1;
    pa.kfsum = kfsum;
    prep_kernel<<<dim3(5234), 256, 0, stream>>>(pa, wsb);

    // 2. fused 6-way projection (mode 1; TM=64 TN=128 BK=64 -> 1152 blocks, 3/CU)
    gemm_bf16<64, 128, 64><<<dim3(36, 32, 1), 256, 0, stream>>>(
        wsb + O_GATEIN + 1536, wsb + O_WPROJT, wsb, nullptr, nullptr, bias_cat, kfsum, nullptr,
        2048, 4608, 768, 2304, 768, 0, 0, 0, 0, 0, 0, 0, 1);

    // 3. kvT GEMM + windowed attention + normalizer (merged full-machine pass)
    kv_attn<<<dim3(736), 256, 0, stream>>>(wsb, kfsum, nrm);

    // 4. lin = (qf @ kvT^T)/nrm -> gate_in slice 0   (BK=64)
    gemm_bf16<32, 64, 64><<<dim3(12, 32, 2), 256, 0, stream>>>(
        wsb + O_PROJ, wsb + O_KVT, wsb, nullptr, wsb + O_GATEIN, nullptr, nrm, nullptr,
        1024, 768, 768, 4608, 768, 0, 2304,
        (long long)1024 * 4608, W2, 0, (long long)1024 * 2304, 0, 0);

    // 5. h1 = relu(gate_in @ Wg1T^T + b_g1)   (BK=64)
    gemm_bf16<32, 64, 64><<<dim3(12, 64, 1), 256, 0, stream>>>(
        wsb + O_GATEIN, wsb + O_WG1T, wsb, nullptr, wsb + O_H1, b_g1, nullptr, nullptr,
        2048, 768, 2304, 2304, 2304, 0, 768, 0, 0, 0, 0, 2, 0);

    // 6. gate = sigmoid(h1 @ Wg2T^T + b_g2); fused = g*lin + (1-g)*win   (BK=64)
    gemm_bf16<32, 64, 64><<<dim3(12, 64, 1), 256, 0, stream>>>(
        wsb + O_H1, wsb + O_WG2T, wsb, nullptr, wsb + O_FUSED, b_g2, nullptr, nullptr,
        2048, 768, 768, 768, 768, 0, 768, 0, 0, 0, 0, 3, 2);

    // 7. out = fused @ WoutT^T + b_out + x   (BK=64)
    gemm_bf16<32, 64, 64><<<dim3(12, 64, 1), 256, 0, stream>>>(
        wsb + O_FUSED, wsb + O_WOUTT, wsb, (float*)d_out, nullptr, b_out, nullptr, x,
        2048, 768, 768, 768, 768, 768, 0, 0, 0, (long long)0, 0, 0, 0);
}